// Round 6
// baseline (272.788 us; speedup 1.0000x reference)
//
#include <hip/hip_runtime.h>

// Problem constants
#define NUM_EMB 1024
#define EMB_DIM 256
#define BATCH   32
#define HW      1024
#define Z_ELEMS (BATCH*EMB_DIM*HW)   // 8388608
#define LOSS_OFF Z_ELEMS
#define IDX_OFF (Z_ELEMS+1)

// ---------------------------------------------------------------------------
// Workspace layout (ws is 256 MiB, poisoned between iterations).
//   float[0]  loss accumulator     float[1](as uint) ticket
//   floats [16    .. 1040)   cnorm[1024]
//   ints   [69632 .. 102400) cand_cnt[32768]  (0 resolved, 1025 overflow)
//   ints   [102400..1150976) cand_idx[32768][32] compacted survivors
//   halves [2359296..2621440) Bt — codebook*1024 fp16, MFMA-B-frag tiled (512 KB)
#define WS_CNORM_OFF 16
#define WS_CNT_IOFF  69632
#define WS_CAND_IOFF 102400
#define WS_BT_HOFF   2359296
#define CAND_CAP     32      // global storage stride
#define CAND_LDS_CAP 20      // per-query in-block append capacity

// Per-query filter threshold: T = T_SLOPE*S1z + T_BIAS (proof in round-1 notes:
// fp16 single pass, codebook scaled x1024 => need 3.82e-6*S1z + 1e-4; chosen
// slope/bias give 1.57x / 3x margin; s1z is a bound input only).
#define T_SLOPE 6.0e-6f
#define T_BIAS  3.0e-4f

typedef __attribute__((ext_vector_type(8))) _Float16 f16x8;
typedef __attribute__((ext_vector_type(4))) float f32x4;

// ---------------------------------------------------------------------------
// K0: tiny prep, 132 blocks: cnorm (exact pairwise tree) + Bt fp16 pack.
__global__ __launch_bounds__(256) void k_prep(const float* __restrict__ cb,
                                              float* __restrict__ ws) {
    const int tid = threadIdx.x;
    const int blk = blockIdx.x;
    if (blk == 0 && tid == 0) { ws[0] = 0.0f; ((unsigned*)ws)[1] = 0u; }
    if (blk < 4) {
        int k = blk * 256 + tid;
        const float* row = cb + (size_t)k * EMB_DIM;
        float hsum[2];
#pragma unroll
        for (int h = 0; h < 2; ++h) {
            const float* a = row + h * 128;
            float r[8];
#pragma unroll
            for (int j = 0; j < 8; ++j) r[j] = __fmul_rn(a[j], a[j]);
            for (int i = 8; i < 128; i += 8)
#pragma unroll
                for (int j = 0; j < 8; ++j)
                    r[j] = __fadd_rn(r[j], __fmul_rn(a[i + j], a[i + j]));
            hsum[h] = __fadd_rn(__fadd_rn(__fadd_rn(r[0], r[1]), __fadd_rn(r[2], r[3])),
                                __fadd_rn(__fadd_rn(r[4], r[5]), __fadd_rn(r[6], r[7])));
        }
        ws[WS_CNORM_OFF + k] = __fadd_rn(hsum[0], hsum[1]);
    } else {
        unsigned u = (unsigned)(blk - 4) * 256 + tid;   // 0..32767
        int lane = u & 63;
        int nt   = (u >> 6) & 15;
        int cc   = (u >> 10) & 7;
        int s    = (u >> 13) & 3;
        int code = s * 256 + nt * 16 + (lane & 15);
        int d0   = cc * 32 + (lane >> 4) * 8;
        const float* cr = cb + (size_t)code * EMB_DIM + d0;
        f16x8 v;
#pragma unroll
        for (int j = 0; j < 8; ++j) v[j] = (_Float16)(cr[j] * 1024.0f);
        _Float16* Bt = (_Float16*)ws + WS_BT_HOFF;
        *(f16x8*)(Bt + ((((size_t)(s * 8 + cc) * 16 + nt) * 64 + lane) * 8)) = v;
    }
}

// ---------------------------------------------------------------------------
// K1: MFMA candidate filter — wave-decoupled: wave w owns slab w end-to-end.
//  - A staged via coalesced float4 z loads -> 8KB fp32 LDS slice -> RNE fp16
//    fragment pack (identical bits to the old pack; conflict-free both sides;
//    depth-1 register prefetch across the 8 slices).
//  - Main loop has ZERO barriers: per wave, 4 nt-groups x 8 chunks of
//    {4 B-frag loads (depth-2, L2-hot) + 16 MFMA}; fold sv = c2 - 2*dot/1024;
//    per-group col-shuffle min merged into a per-wave running slab min;
//    appends under running-min + T (running >= slab >= global min => the
//    proven superset survives every threshold).
//  - One barrier at the end: block-global min, prune to gmin+T, single
//    survivor -> resolved (cnt=0); overflow (>20) -> sentinel full rescan.
__global__ __launch_bounds__(256, 3) void k_filter(const float* __restrict__ z,
                                                   float* __restrict__ ws,
                                                   float* __restrict__ out) {
    __shared__ __attribute__((aligned(16))) _Float16 A_lds[2048 * 8];  // 32 KB
    __shared__ __attribute__((aligned(16))) float st_lds[32][64];      // 8 KB
    __shared__ float wm[256];          // s1 partials, later per-wave slab mins
    __shared__ float tq_s[64];
    __shared__ int   cnt_s[64];
    __shared__ int   bidx_s[64][CAND_LDS_CAP];   // 5 KB
    __shared__ float bval_s[64][CAND_LDS_CAP];   // 5 KB

    const int tid = threadIdx.x;
    const int w = tid >> 6, l = tid & 63;
    const int qb = blockIdx.x, nq0 = qb * 64;
    const int bb = nq0 >> 10, p0 = nq0 & 1023;

    const f16x8* B8 = (const f16x8*)((const _Float16*)ws + WS_BT_HOFF);
    f16x8* Al = (f16x8*)A_lds;

    // B prologue: ks=0,1 of this wave's slab issued before staging (L2-hot,
    // they idle in regs until the main loop).
    f16x8 b[3][4];
#pragma unroll
    for (int t = 0; t < 2; ++t)
#pragma unroll
        for (int i = 0; i < 4; ++i)
            b[t][i] = B8[((size_t)(w * 8 + t) * 16 + i) * 64 + l];

    // ---- A staging: coalesced float4 -> fp32 slice -> fp16 fragments ----
    {
        const float* zb = z + (size_t)bb * EMB_DIM * HW + p0;
        const int q4 = tid & 15, dl = tid >> 4;
        float s1p = 0.0f;
        float4 cur0 = *(const float4*)(zb + (size_t)dl * HW + q4 * 4);
        float4 cur1 = *(const float4*)(zb + (size_t)(16 + dl) * HW + q4 * 4);
        float4 nxt0, nxt1;
#pragma unroll
        for (int s = 0; s < 8; ++s) {
            *(float4*)&st_lds[dl][q4 * 4]      = cur0;
            *(float4*)&st_lds[16 + dl][q4 * 4] = cur1;
            if (s < 7) {   // issue next slice's loads; they fly under convert
                nxt0 = *(const float4*)(zb + (size_t)((s + 1) * 32 + dl) * HW + q4 * 4);
                nxt1 = *(const float4*)(zb + (size_t)((s + 1) * 32 + 16 + dl) * HW + q4 * 4);
            }
            __syncthreads();
            f16x8 g;
#pragma unroll
            for (int j = 0; j < 8; ++j) {
                float v = st_lds[w * 8 + j][l];   // row-contiguous: conflict-free
                s1p += fabsf(v);
                g[j] = (_Float16)v;               // RNE, same bits as old pack
            }
            Al[(s * 4 + (l >> 4)) * 64 + w * 16 + (l & 15)] = g;
            __syncthreads();
            cur0 = nxt0; cur1 = nxt1;
        }
        wm[tid] = s1p;
    }
    if (tid < 64) cnt_s[tid] = 0;
    __syncthreads();
    if (tid < 64)
        tq_s[tid] = fmaf(T_SLOPE,
                         __fadd_rn(__fadd_rn(wm[tid], wm[64 + tid]),
                                   __fadd_rn(wm[128 + tid], wm[192 + tid])),
                         T_BIAS);
    __syncthreads();

    // per-lane constants: c2 for this wave's 16 nt-tiles, tq for its 16 rows
    const float* cn = ws + WS_CNORM_OFF;
    float c2a[16];
#pragma unroll
    for (int nt = 0; nt < 16; ++nt)
        c2a[nt] = cn[w * 256 + nt * 16 + (l & 15)];
    float tqm[4][4];
#pragma unroll
    for (int mt = 0; mt < 4; ++mt)
#pragma unroll
        for (int reg = 0; reg < 4; ++reg)
            tqm[mt][reg] = tq_s[mt * 16 + (l >> 4) * 4 + reg];

    // ---- barrier-free main loop ----
    float rmin[4][4];
#pragma unroll
    for (int mt = 0; mt < 4; ++mt)
#pragma unroll
        for (int reg = 0; reg < 4; ++reg) rmin[mt][reg] = 3.4e38f;

#pragma unroll
    for (int g = 0; g < 4; ++g) {            // nt-group of this wave's slab
        f32x4 acc[4][4];
#pragma unroll
        for (int mt = 0; mt < 4; ++mt)
#pragma unroll
            for (int i = 0; i < 4; ++i) acc[mt][i] = (f32x4)(0.0f);
#pragma unroll
        for (int c = 0; c < 8; ++c) {        // K chunk
            const int ks = g * 8 + c;
            if (ks + 2 < 32) {               // depth-2 B prefetch
                const int k2 = ks + 2, c2i = k2 & 7, g2 = k2 >> 3;
#pragma unroll
                for (int i = 0; i < 4; ++i)
                    b[k2 % 3][i] = B8[((size_t)(w * 8 + c2i) * 16 + g2 * 4 + i) * 64 + l];
            }
#pragma unroll
            for (int mt = 0; mt < 4; ++mt) {
                f16x8 av = Al[(c * 4 + mt) * 64 + l];
#pragma unroll
                for (int i = 0; i < 4; ++i)
                    acc[mt][i] = __builtin_amdgcn_mfma_f32_16x16x32_f16(av, b[ks % 3][i], acc[mt][i], 0, 0, 0);
            }
        }
        // fold + group min (wave-local)
        float gm[4][4];
#pragma unroll
        for (int mt = 0; mt < 4; ++mt)
#pragma unroll
            for (int reg = 0; reg < 4; ++reg) gm[mt][reg] = 3.4e38f;
#pragma unroll
        for (int mt = 0; mt < 4; ++mt)
#pragma unroll
            for (int i = 0; i < 4; ++i)
#pragma unroll
                for (int reg = 0; reg < 4; ++reg) {
                    float sv = fmaf(-0.001953125f, acc[mt][i][reg], c2a[g * 4 + i]);  // -2/1024
                    acc[mt][i][reg] = sv;
                    gm[mt][reg] = fminf(gm[mt][reg], sv);
                }
#pragma unroll
        for (int msk = 1; msk < 16; msk <<= 1)
#pragma unroll
            for (int mt = 0; mt < 4; ++mt)
#pragma unroll
                for (int reg = 0; reg < 4; ++reg)
                    gm[mt][reg] = fminf(gm[mt][reg], __shfl_xor(gm[mt][reg], msk, 64));
#pragma unroll
        for (int mt = 0; mt < 4; ++mt)
#pragma unroll
            for (int reg = 0; reg < 4; ++reg)
                rmin[mt][reg] = fminf(rmin[mt][reg], gm[mt][reg]);
        // appends under running-min + T
#pragma unroll
        for (int mt = 0; mt < 4; ++mt)
#pragma unroll
            for (int reg = 0; reg < 4; ++reg) {
                const int m = mt * 16 + (l >> 4) * 4 + reg;
                const float th = rmin[mt][reg] + tqm[mt][reg];
#pragma unroll
                for (int i = 0; i < 4; ++i) {
                    float sv = acc[mt][i][reg];
                    if (sv <= th) {
                        int kg = w * 256 + (g * 4 + i) * 16 + (l & 15);
                        int pos = atomicAdd(&cnt_s[m], 1);
                        if (pos < CAND_LDS_CAP) { bidx_s[m][pos] = kg; bval_s[m][pos] = sv; }
                    }
                }
            }
    }
    // publish per-wave slab mins
    if ((l & 15) == 0) {
#pragma unroll
        for (int mt = 0; mt < 4; ++mt)
#pragma unroll
            for (int reg = 0; reg < 4; ++reg)
                wm[w * 64 + mt * 16 + (l >> 4) * 4 + reg] = rmin[mt][reg];
    }
    __syncthreads();   // all appends + slab mins visible

    if (tid < 64) {
        int n = nq0 + tid;
        int c = cnt_s[tid];
        int* cnt_g  = (int*)ws + WS_CNT_IOFF;
        int* cand_g = (int*)ws + WS_CAND_IOFF;
        if (c > CAND_LDS_CAP) {
            cnt_g[n] = 1025;                  // overflow sentinel -> full rescan
        } else {
            float gmin = fminf(fminf(wm[tid], wm[64 + tid]),
                               fminf(wm[128 + tid], wm[192 + tid]));
            float th = gmin + tq_s[tid];
            int m = 0, keep = 0;
            for (int j = 0; j < c; ++j) {
                if (bval_s[tid][j] <= th) {
                    cand_g[(size_t)n * CAND_CAP + m] = bidx_s[tid][j];
                    if (m == 0) keep = bidx_s[tid][j];
                    ++m;
                }
            }
            if (m == 1) {
                out[IDX_OFF + n] = (float)keep;   // resolved here
                cnt_g[n] = 0;
            } else {
                cnt_g[n] = m;
            }
        }
    }
}

// ---------------------------------------------------------------------------
// K2: fused exact znorm + rescore + gather + loss. (unchanged, passing r5)
__global__ __launch_bounds__(256) void k_resgather(const float* __restrict__ z,
                                                   const float* __restrict__ cb,
                                                   float* __restrict__ ws,
                                                   float* __restrict__ out) {
    __shared__ __attribute__((aligned(16))) float z_lds[256][64];   // 64 KB
    __shared__ float s_half[64][33];                                // 8.4 KB
    __shared__ int   idx_s[64];
    __shared__ int   c_s[64];
    __shared__ int   offI[64];
    __shared__ int   ovf_s[64];
    __shared__ float zh_s[64];
    __shared__ float zn_s[64];
    __shared__ unsigned long long key_s[64];
    __shared__ float s_red[4];
    __shared__ int   work_s;

    const int tid = threadIdx.x;
    const int w = tid >> 6, l = tid & 63;
    const int n0 = blockIdx.x * 64;
    const int b = n0 >> 10, p0 = n0 & 1023;
    const int* cnt  = (const int*)ws + WS_CNT_IOFF;
    const int* cand = (const int*)ws + WS_CAND_IOFF;
    const float* cn = ws + WS_CNORM_OFF;

    if (tid < 64) {   // wave 0: per-query state + prefix scan + work flag
        int c = cnt[n0 + tid];
        int ov = (c > CAND_LDS_CAP) ? 1 : 0;
        ovf_s[tid] = ov;
        int cc = (ov || c < 2) ? 0 : c;
        c_s[tid] = cc;
        key_s[tid] = ~0ULL;
        if (cc == 0 && !ov) idx_s[tid] = (int)out[IDX_OFF + n0 + tid];  // filter-resolved
        int v = cc;
#pragma unroll
        for (int off = 1; off < 64; off <<= 1) {
            int u = __shfl_up(v, off, 64);
            if (l >= off) v += u;
        }
        offI[tid] = v;
        unsigned long long ball = __ballot(ov != 0);
        if (tid == 63) work_s = v + (ball ? 1 : 0);
    }

    // stage z tile: [d][q] fp32, float4 coalesced (exact bits); always needed
    {
        const float* zb = z + (size_t)b * EMB_DIM * HW + p0;
        const int q4 = tid & 15, g = tid >> 4;
#pragma unroll 4
        for (int r = 0; r < 16; ++r) {
            int d = r * 16 + g;
            float4 vv = *(const float4*)(zb + (size_t)d * HW + q4 * 4);
            *(float4*)&z_lds[d][q4 * 4] = vv;
        }
    }
    __syncthreads();

    if (work_s != 0) {
        // znorm from z_lds: exact pairwise tree, 2 threads/query (128-d seam)
        float hf0 = 0.0f;
        if (tid < 128) {
            const int q = tid & 63, h = tid >> 6;
            float r[8];
#pragma unroll
            for (int j = 0; j < 8; ++j) {
                float v = z_lds[h * 128 + j][q];
                r[j] = __fmul_rn(v, v);
            }
            for (int i = 8; i < 128; i += 8)
#pragma unroll
                for (int j = 0; j < 8; ++j) {
                    float v = z_lds[h * 128 + i + j][q];
                    r[j] = __fadd_rn(r[j], __fmul_rn(v, v));
                }
            float hf = __fadd_rn(__fadd_rn(__fadd_rn(r[0], r[1]), __fadd_rn(r[2], r[3])),
                                 __fadd_rn(__fadd_rn(r[4], r[5]), __fadd_rn(r[6], r[7])));
            if (h) zh_s[q] = hf; else hf0 = hf;
        }
        __syncthreads();
        if (tid < 64) zn_s[tid] = __fadd_rn(hf0, zh_s[tid]);   // exact fadd(half0, half1)
        __syncthreads();

        // candidate-per-thread exact rescore
        const int C = offI[63];
        for (int t = tid; t < C; t += 256) {
            int lo = 0, hi = 63;
            while (lo < hi) { int mid = (lo + hi) >> 1; if (offI[mid] > t) hi = mid; else lo = mid + 1; }
            const int m = lo;
            const int j = t - (m ? offI[m - 1] : 0);
            const int n = n0 + m;
            const int kk = cand[(size_t)n * CAND_CAP + j];
            const float* r = cb + (size_t)kk * EMB_DIM;
            float dot = 0.0f;
#pragma unroll 8
            for (int d = 0; d < EMB_DIM; ++d)
                dot = fmaf(z_lds[d][m], r[d], dot);
            float t1 = __fadd_rn(zn_s[m], cn[kk]);
            float sv = __fadd_rn(t1, __fmul_rn(-2.0f, dot));
            unsigned ue = __float_as_uint(sv);
            ue = (ue >> 31) ? ~ue : (ue | 0x80000000u);
            atomicMin(&key_s[m], ((unsigned long long)ue << 32) | (unsigned)kk);
        }

        // overflow queries (rare): distributed exact full scan, wave per query
        for (int m = w; m < 64; m += 4) {
            if (!ovf_s[m]) continue;
            const float z2 = zn_s[m];
            float sv = 3.4e38f; int kk = NUM_EMB;
            for (int k0 = l; k0 < NUM_EMB; k0 += 64) {
                const float* r = cb + (size_t)k0 * EMB_DIM;
                float dot = 0.0f;
#pragma unroll 8
                for (int d = 0; d < EMB_DIM; ++d)
                    dot = fmaf(z_lds[d][m], r[d], dot);
                float t1 = __fadd_rn(z2, cn[k0]);
                float s2 = __fadd_rn(t1, __fmul_rn(-2.0f, dot));
                if (s2 < sv) { sv = s2; kk = k0; }   // ascending k: < keeps first
            }
#pragma unroll
            for (int off = 32; off; off >>= 1) {
                float osv = __shfl_xor(sv, off, 64);
                int   okk = __shfl_xor(kk, off, 64);
                if (osv < sv || (osv == sv && okk < kk)) { sv = osv; kk = okk; }
            }
            if (l == 0) {
                unsigned ue = __float_as_uint(sv);
                ue = (ue >> 31) ? ~ue : (ue | 0x80000000u);
                key_s[m] = ((unsigned long long)ue << 32) | (unsigned)kk;
            }
        }
        __syncthreads();
        if (tid < 64 && (c_s[tid] > 0 || ovf_s[tid])) {
            int kk = (int)(unsigned)(key_s[tid] & 0xFFFFFFFFULL);
            idx_s[tid] = kk;
            out[IDX_OFF + n0 + tid] = (float)kk;
        }
        __syncthreads();
    }

    // ---- gather phase: per-thread arithmetic/order bit-identical ----
    const int p    = tid & 63;
    const int cgrp = tid >> 6;
    const int row  = tid >> 2;
    const int q4g  = tid & 3;
    float* orow = out + (size_t)b * EMB_DIM * HW + p0 + p;

    float acc = 0.0f;
#pragma unroll 1
    for (int d0 = 0; d0 < EMB_DIM; d0 += 64) {
        const float* cr = cb + (size_t)idx_s[row] * EMB_DIM + d0;
#pragma unroll 1
        for (int h = 0; h < 2; ++h) {
#pragma unroll
            for (int pass = 0; pass < 2; ++pass) {
                int s = q4g + pass * 4;
                int gg = s >> 1, j00 = (s & 1) * 4;
                *(float4*)&s_half[row][gg * 8 + j00] = *(const float4*)(cr + gg * 16 + h * 8 + j00);
            }
            __syncthreads();
#pragma unroll
            for (int j0 = 0; j0 < 8; ++j0) {
                int c = cgrp * 16 + h * 8 + j0;
                float zq = s_half[p][cgrp * 8 + j0];
                float zv = z_lds[d0 + c][p];
                float d  = zq - zv;
                orow[(size_t)(d0 + c) * HW] = zv + d;
                acc += d * d;
            }
            __syncthreads();
        }
    }
#pragma unroll
    for (int off = 32; off > 0; off >>= 1) acc += __shfl_down(acc, off, 64);
    if ((tid & 63) == 0) s_red[tid >> 6] = acc;
    __syncthreads();
    if (tid == 0) {
        atomicAdd(ws, s_red[0] + s_red[1] + s_red[2] + s_red[3]);
        __threadfence();
        unsigned old = atomicAdd((unsigned int*)ws + 1, 1u);
        if (old == 511u) {
            float total = atomicAdd(ws, 0.0f);
            out[LOSS_OFF] = 1.25f * (total * (1.0f / 8388608.0f));
        }
    }
}

// ---------------------------------------------------------------------------
extern "C" void kernel_launch(void* const* d_in, const int* in_sizes, int n_in,
                              void* d_out, int out_size, void* d_ws, size_t ws_size,
                              hipStream_t stream) {
    const float* z  = (const float*)d_in[0];
    const float* cb = (const float*)d_in[1];
    float* out = (float*)d_out;
    float* ws  = (float*)d_ws;

    k_prep     <<<132, 256, 0, stream>>>(cb, ws);
    k_filter   <<<512, 256, 0, stream>>>(z, ws, out);
    k_resgather<<<512, 256, 0, stream>>>(z, cb, ws, out);
}

// Round 7
// 157.874 us; speedup vs baseline: 1.7279x; 1.7279x over previous
//
#include <hip/hip_runtime.h>

// Problem constants
#define NUM_EMB 1024
#define EMB_DIM 256
#define BATCH   32
#define HW      1024
#define Z_ELEMS (BATCH*EMB_DIM*HW)   // 8388608
#define LOSS_OFF Z_ELEMS
#define IDX_OFF (Z_ELEMS+1)

// ---------------------------------------------------------------------------
// Workspace layout (ws is 256 MiB, poisoned between iterations).
//   float[0]  loss accumulator     float[1](as uint) ticket
//   floats [16    .. 1040)   cnorm[1024]
//   ints   [69632 .. 102400) cand_cnt[32768]  (0 resolved, 1025 overflow)
//   ints   [102400..1150976) cand_idx[32768][32] compacted survivors
//   halves [2359296..2621440) Bt — codebook*1024 fp16, MFMA-B-frag tiled (512 KB)
#define WS_CNORM_OFF 16
#define WS_CNT_IOFF  69632
#define WS_CAND_IOFF 102400
#define WS_BT_HOFF   2359296
#define CAND_CAP  32

// Per-query filter threshold: T = T_SLOPE*S1z + T_BIAS (proof in round-1 notes:
// fp16 single pass, codebook scaled x1024 => need 3.82e-6*S1z + 1e-4; chosen
// slope/bias give 1.57x / 3x margin; s1z is a bound input only).
#define T_SLOPE 6.0e-6f
#define T_BIAS  3.0e-4f

typedef __attribute__((ext_vector_type(8))) _Float16 f16x8;
typedef __attribute__((ext_vector_type(4))) float f32x4;

// ---------------------------------------------------------------------------
// K0: tiny prep, 132 blocks: cnorm (exact pairwise tree) + Bt fp16 pack.
__global__ __launch_bounds__(256) void k_prep(const float* __restrict__ cb,
                                              float* __restrict__ ws) {
    const int tid = threadIdx.x;
    const int blk = blockIdx.x;
    if (blk == 0 && tid == 0) { ws[0] = 0.0f; ((unsigned*)ws)[1] = 0u; }
    if (blk < 4) {
        int k = blk * 256 + tid;
        const float* row = cb + (size_t)k * EMB_DIM;
        float hsum[2];
#pragma unroll
        for (int h = 0; h < 2; ++h) {
            const float* a = row + h * 128;
            float r[8];
#pragma unroll
            for (int j = 0; j < 8; ++j) r[j] = __fmul_rn(a[j], a[j]);
            for (int i = 8; i < 128; i += 8)
#pragma unroll
                for (int j = 0; j < 8; ++j)
                    r[j] = __fadd_rn(r[j], __fmul_rn(a[i + j], a[i + j]));
            hsum[h] = __fadd_rn(__fadd_rn(__fadd_rn(r[0], r[1]), __fadd_rn(r[2], r[3])),
                                __fadd_rn(__fadd_rn(r[4], r[5]), __fadd_rn(r[6], r[7])));
        }
        ws[WS_CNORM_OFF + k] = __fadd_rn(hsum[0], hsum[1]);
    } else {
        unsigned u = (unsigned)(blk - 4) * 256 + tid;   // 0..32767
        int lane = u & 63;
        int nt   = (u >> 6) & 15;
        int cc   = (u >> 10) & 7;
        int s    = (u >> 13) & 3;
        int code = s * 256 + nt * 16 + (lane & 15);
        int d0   = cc * 32 + (lane >> 4) * 8;
        const float* cr = cb + (size_t)code * EMB_DIM + d0;
        f16x8 v;
#pragma unroll
        for (int j = 0; j < 8; ++j) v[j] = (_Float16)(cr[j] * 1024.0f);
        _Float16* Bt = (_Float16*)ws + WS_BT_HOFF;
        *(f16x8*)(Bt + ((((size_t)(s * 8 + cc) * 16 + nt) * 64 + lane) * 8)) = v;
    }
}

// ---------------------------------------------------------------------------
// K1: MFMA candidate filter, all 4 slabs per block. Round-5 structure verbatim;
// ONLY change: __launch_bounds__(256, 2) instead of (256, 3). The 3-wave
// clause capped VGPR at 128, below the ~150 the written depth-2 B pipeline
// needs, so the compiler de-pipelined (observed VGPR 84) and every MFMA group
// serialized on a full L2 round-trip. (256,2) raises the cap to 256.
__global__ __launch_bounds__(256, 2) void k_filter(const float* __restrict__ z,
                                                   float* __restrict__ ws,
                                                   float* __restrict__ out) {
    __shared__ __attribute__((aligned(16))) _Float16 A_lds[2048 * 8];  // 32 KB
    __shared__ float wm[256];
    __shared__ float rmin_s[64];
    __shared__ float tq_s[64];
    __shared__ float thr_s[64];
    __shared__ int   cnt_s[64];
    __shared__ int   bidx_s[64][CAND_CAP];   // 8 KB
    __shared__ float bval_s[64][CAND_CAP];   // 8 KB

    const int tid = threadIdx.x;
    const int w = tid >> 6, l = tid & 63;
    const int qb = blockIdx.x, nq0 = qb * 64;
    const int bb = nq0 >> 10, p0 = nq0 & 1023;

    const f16x8* B8 = (const f16x8*)((const _Float16*)ws + WS_BT_HOFF);
    f16x8* Al = (f16x8*)A_lds;

    // prologue: issue B loads for steps 0,1 so they fly under A staging
    f16x8 b[3][4];
#pragma unroll
    for (int t = 0; t < 2; ++t)
#pragma unroll
        for (int nt = 0; nt < 4; ++nt)
            b[t][nt] = B8[((size_t)(t * 16) + w * 4 + nt) * 64 + l];

    // stage A from fp32 z + s1 partial
    {
        const float* zq = z + (size_t)bb * EMB_DIM * HW + p0 + l;
        float s1p = 0.0f;
#pragma unroll
        for (int i8 = 0; i8 < 8; ++i8) {
            const int d0 = w * 64 + i8 * 8;
            float v[8];
#pragma unroll
            for (int j = 0; j < 8; ++j) v[j] = zq[(size_t)(d0 + j) * HW];
            f16x8 g;
#pragma unroll
            for (int j = 0; j < 8; ++j) { g[j] = (_Float16)v[j]; s1p += fabsf(v[j]); }
            const int c = d0 >> 5, kh = (d0 >> 3) & 3;
            Al[(c * 4 + (l >> 4)) * 64 + kh * 16 + (l & 15)] = g;
        }
        wm[tid] = s1p;
    }
    if (tid < 64) { cnt_s[tid] = 0; rmin_s[tid] = 3.4e38f; }
    __syncthreads();
    if (tid < 64)
        tq_s[tid] = fmaf(T_SLOPE,
                         __fadd_rn(__fadd_rn(wm[tid], wm[64 + tid]),
                                   __fadd_rn(wm[128 + tid], wm[192 + tid])),
                         T_BIAS);
    __syncthreads();

    const float* cn = ws + WS_CNORM_OFF;
    f32x4 acc[4][4];
#pragma unroll
    for (int mt = 0; mt < 4; ++mt)
#pragma unroll
        for (int nt = 0; nt < 4; ++nt) acc[mt][nt] = (f32x4)(0.0f);

#pragma unroll
    for (int t = 0; t < 32; ++t) {           // t = slab*8 + chunk
        const int c = t & 7, s = t >> 3;
        if (t + 2 < 32) {                    // depth-2 B prefetch
            const int t2 = t + 2;
#pragma unroll
            for (int nt = 0; nt < 4; ++nt)
                b[t2 % 3][nt] = B8[((size_t)(t2 * 16) + w * 4 + nt) * 64 + l];
        }
#pragma unroll
        for (int mt = 0; mt < 4; ++mt) {
            f16x8 av = Al[(c * 4 + mt) * 64 + l];
#pragma unroll
            for (int nt = 0; nt < 4; ++nt)
                acc[mt][nt] = __builtin_amdgcn_mfma_f32_16x16x32_f16(av, b[t % 3][nt], acc[mt][nt], 0, 0, 0);
        }
        if (c == 7) {
            // ---- slab epilogue (B loads for next slab already in flight) ----
            float c2[4];
#pragma unroll
            for (int nt = 0; nt < 4; ++nt)
                c2[nt] = cn[s * 256 + (w * 4 + nt) * 16 + (l & 15)];
            float vmin[4][4];
#pragma unroll
            for (int mt = 0; mt < 4; ++mt)
#pragma unroll
                for (int reg = 0; reg < 4; ++reg) vmin[mt][reg] = 3.4e38f;
#pragma unroll
            for (int mt = 0; mt < 4; ++mt)
#pragma unroll
                for (int nt = 0; nt < 4; ++nt)
#pragma unroll
                    for (int reg = 0; reg < 4; ++reg) {
                        float sv = fmaf(-0.001953125f, acc[mt][nt][reg], c2[nt]);  // -2/1024
                        acc[mt][nt][reg] = sv;
                        vmin[mt][reg] = fminf(vmin[mt][reg], sv);
                    }
#pragma unroll
            for (int msk = 1; msk < 16; msk <<= 1)
#pragma unroll
                for (int mt = 0; mt < 4; ++mt)
#pragma unroll
                    for (int reg = 0; reg < 4; ++reg)
                        vmin[mt][reg] = fminf(vmin[mt][reg], __shfl_xor(vmin[mt][reg], msk, 64));
            if ((l & 15) == 0) {
#pragma unroll
                for (int mt = 0; mt < 4; ++mt)
#pragma unroll
                    for (int reg = 0; reg < 4; ++reg)
                        wm[w * 64 + mt * 16 + (l >> 4) * 4 + reg] = vmin[mt][reg];
            }
            __syncthreads();
            if (tid < 64) {
                float smin = fminf(fminf(wm[tid], wm[64 + tid]),
                                   fminf(wm[128 + tid], wm[192 + tid]));
                float rm = fminf(rmin_s[tid], smin);
                rmin_s[tid] = rm;
                thr_s[tid] = rm + tq_s[tid];
            }
            __syncthreads();
            // append candidates under running threshold
#pragma unroll
            for (int mt = 0; mt < 4; ++mt)
#pragma unroll
                for (int reg = 0; reg < 4; ++reg) {
                    int m = mt * 16 + (l >> 4) * 4 + reg;
                    float th = thr_s[m];
#pragma unroll
                    for (int nt = 0; nt < 4; ++nt) {
                        float sv = acc[mt][nt][reg];
                        if (sv <= th) {
                            int kg = s * 256 + (w * 4 + nt) * 16 + (l & 15);
                            int pos = atomicAdd(&cnt_s[m], 1);
                            if (pos < CAND_CAP) { bidx_s[m][pos] = kg; bval_s[m][pos] = sv; }
                        }
                    }
                }
            // re-zero accumulators for next slab
#pragma unroll
            for (int mt = 0; mt < 4; ++mt)
#pragma unroll
                for (int nt = 0; nt < 4; ++nt) acc[mt][nt] = (f32x4)(0.0f);
        }
    }
    __syncthreads();   // all appends visible
    if (tid < 64) {
        int n = nq0 + tid;
        int c = cnt_s[tid];
        int* cnt_g  = (int*)ws + WS_CNT_IOFF;
        int* cand_g = (int*)ws + WS_CAND_IOFF;
        if (c > CAND_CAP) {
            cnt_g[n] = 1025;                  // overflow sentinel -> full rescan
        } else {
            float th = thr_s[tid];            // global min + T (after slab 3)
            int m = 0, keep = 0;
            for (int j = 0; j < c; ++j) {
                if (bval_s[tid][j] <= th) {
                    cand_g[(size_t)n * CAND_CAP + m] = bidx_s[tid][j];
                    if (m == 0) keep = bidx_s[tid][j];
                    ++m;
                }
            }
            if (m == 1) {
                out[IDX_OFF + n] = (float)keep;   // resolved here
                cnt_g[n] = 0;
            } else {
                cnt_g[n] = m;
            }
        }
    }
}

// ---------------------------------------------------------------------------
// K2: fused exact znorm + rescore + gather + loss. (unchanged, passing r5)
__global__ __launch_bounds__(256) void k_resgather(const float* __restrict__ z,
                                                   const float* __restrict__ cb,
                                                   float* __restrict__ ws,
                                                   float* __restrict__ out) {
    __shared__ __attribute__((aligned(16))) float z_lds[256][64];   // 64 KB
    __shared__ float s_half[64][33];                                // 8.4 KB
    __shared__ int   idx_s[64];
    __shared__ int   c_s[64];
    __shared__ int   offI[64];
    __shared__ int   ovf_s[64];
    __shared__ float zh_s[64];
    __shared__ float zn_s[64];
    __shared__ unsigned long long key_s[64];
    __shared__ float s_red[4];
    __shared__ int   work_s;

    const int tid = threadIdx.x;
    const int w = tid >> 6, l = tid & 63;
    const int n0 = blockIdx.x * 64;
    const int b = n0 >> 10, p0 = n0 & 1023;
    const int* cnt  = (const int*)ws + WS_CNT_IOFF;
    const int* cand = (const int*)ws + WS_CAND_IOFF;
    const float* cn = ws + WS_CNORM_OFF;

    if (tid < 64) {   // wave 0: per-query state + prefix scan + work flag
        int c = cnt[n0 + tid];
        int ov = (c > CAND_CAP) ? 1 : 0;
        ovf_s[tid] = ov;
        int cc = (ov || c < 2) ? 0 : c;
        c_s[tid] = cc;
        key_s[tid] = ~0ULL;
        if (cc == 0 && !ov) idx_s[tid] = (int)out[IDX_OFF + n0 + tid];  // filter-resolved
        int v = cc;
#pragma unroll
        for (int off = 1; off < 64; off <<= 1) {
            int u = __shfl_up(v, off, 64);
            if (l >= off) v += u;
        }
        offI[tid] = v;
        unsigned long long ball = __ballot(ov != 0);
        if (tid == 63) work_s = v + (ball ? 1 : 0);
    }

    // stage z tile: [d][q] fp32, float4 coalesced (exact bits); always needed
    {
        const float* zb = z + (size_t)b * EMB_DIM * HW + p0;
        const int q4 = tid & 15, g = tid >> 4;
#pragma unroll 4
        for (int r = 0; r < 16; ++r) {
            int d = r * 16 + g;
            float4 vv = *(const float4*)(zb + (size_t)d * HW + q4 * 4);
            *(float4*)&z_lds[d][q4 * 4] = vv;
        }
    }
    __syncthreads();

    if (work_s != 0) {
        // znorm from z_lds: exact pairwise tree, 2 threads/query (128-d seam)
        float hf0 = 0.0f;
        if (tid < 128) {
            const int q = tid & 63, h = tid >> 6;
            float r[8];
#pragma unroll
            for (int j = 0; j < 8; ++j) {
                float v = z_lds[h * 128 + j][q];
                r[j] = __fmul_rn(v, v);
            }
            for (int i = 8; i < 128; i += 8)
#pragma unroll
                for (int j = 0; j < 8; ++j) {
                    float v = z_lds[h * 128 + i + j][q];
                    r[j] = __fadd_rn(r[j], __fmul_rn(v, v));
                }
            float hf = __fadd_rn(__fadd_rn(__fadd_rn(r[0], r[1]), __fadd_rn(r[2], r[3])),
                                 __fadd_rn(__fadd_rn(r[4], r[5]), __fadd_rn(r[6], r[7])));
            if (h) zh_s[q] = hf; else hf0 = hf;
        }
        __syncthreads();
        if (tid < 64) zn_s[tid] = __fadd_rn(hf0, zh_s[tid]);   // exact fadd(half0, half1)
        __syncthreads();

        // candidate-per-thread exact rescore
        const int C = offI[63];
        for (int t = tid; t < C; t += 256) {
            int lo = 0, hi = 63;
            while (lo < hi) { int mid = (lo + hi) >> 1; if (offI[mid] > t) hi = mid; else lo = mid + 1; }
            const int m = lo;
            const int j = t - (m ? offI[m - 1] : 0);
            const int n = n0 + m;
            const int kk = cand[(size_t)n * CAND_CAP + j];
            const float* r = cb + (size_t)kk * EMB_DIM;
            float dot = 0.0f;
#pragma unroll 8
            for (int d = 0; d < EMB_DIM; ++d)
                dot = fmaf(z_lds[d][m], r[d], dot);
            float t1 = __fadd_rn(zn_s[m], cn[kk]);
            float sv = __fadd_rn(t1, __fmul_rn(-2.0f, dot));
            unsigned ue = __float_as_uint(sv);
            ue = (ue >> 31) ? ~ue : (ue | 0x80000000u);
            atomicMin(&key_s[m], ((unsigned long long)ue << 32) | (unsigned)kk);
        }

        // overflow queries (rare): distributed exact full scan, wave per query
        for (int m = w; m < 64; m += 4) {
            if (!ovf_s[m]) continue;
            const float z2 = zn_s[m];
            float sv = 3.4e38f; int kk = NUM_EMB;
            for (int k0 = l; k0 < NUM_EMB; k0 += 64) {
                const float* r = cb + (size_t)k0 * EMB_DIM;
                float dot = 0.0f;
#pragma unroll 8
                for (int d = 0; d < EMB_DIM; ++d)
                    dot = fmaf(z_lds[d][m], r[d], dot);
                float t1 = __fadd_rn(z2, cn[k0]);
                float s2 = __fadd_rn(t1, __fmul_rn(-2.0f, dot));
                if (s2 < sv) { sv = s2; kk = k0; }   // ascending k: < keeps first
            }
#pragma unroll
            for (int off = 32; off; off >>= 1) {
                float osv = __shfl_xor(sv, off, 64);
                int   okk = __shfl_xor(kk, off, 64);
                if (osv < sv || (osv == sv && okk < kk)) { sv = osv; kk = okk; }
            }
            if (l == 0) {
                unsigned ue = __float_as_uint(sv);
                ue = (ue >> 31) ? ~ue : (ue | 0x80000000u);
                key_s[m] = ((unsigned long long)ue << 32) | (unsigned)kk;
            }
        }
        __syncthreads();
        if (tid < 64 && (c_s[tid] > 0 || ovf_s[tid])) {
            int kk = (int)(unsigned)(key_s[tid] & 0xFFFFFFFFULL);
            idx_s[tid] = kk;
            out[IDX_OFF + n0 + tid] = (float)kk;
        }
        __syncthreads();
    }

    // ---- gather phase: per-thread arithmetic/order bit-identical ----
    const int p    = tid & 63;
    const int cgrp = tid >> 6;
    const int row  = tid >> 2;
    const int q4g  = tid & 3;
    float* orow = out + (size_t)b * EMB_DIM * HW + p0 + p;

    float acc = 0.0f;
#pragma unroll 1
    for (int d0 = 0; d0 < EMB_DIM; d0 += 64) {
        const float* cr = cb + (size_t)idx_s[row] * EMB_DIM + d0;
#pragma unroll 1
        for (int h = 0; h < 2; ++h) {
#pragma unroll
            for (int pass = 0; pass < 2; ++pass) {
                int s = q4g + pass * 4;
                int gg = s >> 1, j00 = (s & 1) * 4;
                *(float4*)&s_half[row][gg * 8 + j00] = *(const float4*)(cr + gg * 16 + h * 8 + j00);
            }
            __syncthreads();
#pragma unroll
            for (int j0 = 0; j0 < 8; ++j0) {
                int c = cgrp * 16 + h * 8 + j0;
                float zq = s_half[p][cgrp * 8 + j0];
                float zv = z_lds[d0 + c][p];
                float d  = zq - zv;
                orow[(size_t)(d0 + c) * HW] = zv + d;
                acc += d * d;
            }
            __syncthreads();
        }
    }
#pragma unroll
    for (int off = 32; off > 0; off >>= 1) acc += __shfl_down(acc, off, 64);
    if ((tid & 63) == 0) s_red[tid >> 6] = acc;
    __syncthreads();
    if (tid == 0) {
        atomicAdd(ws, s_red[0] + s_red[1] + s_red[2] + s_red[3]);
        __threadfence();
        unsigned old = atomicAdd((unsigned int*)ws + 1, 1u);
        if (old == 511u) {
            float total = atomicAdd(ws, 0.0f);
            out[LOSS_OFF] = 1.25f * (total * (1.0f / 8388608.0f));
        }
    }
}

// ---------------------------------------------------------------------------
extern "C" void kernel_launch(void* const* d_in, const int* in_sizes, int n_in,
                              void* d_out, int out_size, void* d_ws, size_t ws_size,
                              hipStream_t stream) {
    const float* z  = (const float*)d_in[0];
    const float* cb = (const float*)d_in[1];
    float* out = (float*)d_out;
    float* ws  = (float*)d_ws;

    k_prep     <<<132, 256, 0, stream>>>(cb, ws);
    k_filter   <<<512, 256, 0, stream>>>(z, ws, out);
    k_resgather<<<512, 256, 0, stream>>>(z, cb, ws, out);
}

// Round 9
// 155.182 us; speedup vs baseline: 1.7579x; 1.0174x over previous
//
#include <hip/hip_runtime.h>

// Problem constants
#define NUM_EMB 1024
#define EMB_DIM 256
#define BATCH   32
#define HW      1024
#define Z_ELEMS (BATCH*EMB_DIM*HW)   // 8388608
#define LOSS_OFF Z_ELEMS
#define IDX_OFF (Z_ELEMS+1)

// ---------------------------------------------------------------------------
// Workspace layout (ws is 256 MiB, poisoned between iterations; the ~43us
// 256MiB fill sits inside the timed loop and is the uncontrollable floor).
//   float[0]  loss accumulator     float[1](as uint) ticket
//   floats [16    .. 1040)   cnorm[1024]
//   ints   [69632 .. 102400) cand_cnt[32768]  (0 resolved, 1025 overflow)
//   ints   [102400..1150976) cand_idx[32768][32] compacted survivors
//   halves [2359296..2621440) Bt — codebook*1024 fp16, MFMA-B-frag tiled (512 KB)
#define WS_CNORM_OFF 16
#define WS_CNT_IOFF  69632
#define WS_CAND_IOFF 102400
#define WS_BT_HOFF   2359296
#define CAND_CAP  32

// Per-query filter threshold: T = T_SLOPE*S1z + T_BIAS (proof in round-1 notes:
// fp16 single pass, codebook scaled x1024 => need 3.82e-6*S1z + 1e-4; chosen
// slope/bias give 1.57x / 3x margin; s1z is a bound input only).
#define T_SLOPE 6.0e-6f
#define T_BIAS  3.0e-4f

typedef __attribute__((ext_vector_type(8))) _Float16 f16x8;
typedef __attribute__((ext_vector_type(4))) float f32x4;

// ---------------------------------------------------------------------------
// K0: tiny prep, 132 blocks: cnorm (exact pairwise tree) + Bt fp16 pack.
__global__ __launch_bounds__(256) void k_prep(const float* __restrict__ cb,
                                              float* __restrict__ ws) {
    const int tid = threadIdx.x;
    const int blk = blockIdx.x;
    if (blk == 0 && tid == 0) { ws[0] = 0.0f; ((unsigned*)ws)[1] = 0u; }
    if (blk < 4) {
        int k = blk * 256 + tid;
        const float* row = cb + (size_t)k * EMB_DIM;
        float hsum[2];
#pragma unroll
        for (int h = 0; h < 2; ++h) {
            const float* a = row + h * 128;
            float r[8];
#pragma unroll
            for (int j = 0; j < 8; ++j) r[j] = __fmul_rn(a[j], a[j]);
            for (int i = 8; i < 128; i += 8)
#pragma unroll
                for (int j = 0; j < 8; ++j)
                    r[j] = __fadd_rn(r[j], __fmul_rn(a[i + j], a[i + j]));
            hsum[h] = __fadd_rn(__fadd_rn(__fadd_rn(r[0], r[1]), __fadd_rn(r[2], r[3])),
                                __fadd_rn(__fadd_rn(r[4], r[5]), __fadd_rn(r[6], r[7])));
        }
        ws[WS_CNORM_OFF + k] = __fadd_rn(hsum[0], hsum[1]);
    } else {
        unsigned u = (unsigned)(blk - 4) * 256 + tid;   // 0..32767
        int lane = u & 63;
        int nt   = (u >> 6) & 15;
        int cc   = (u >> 10) & 7;
        int s    = (u >> 13) & 3;
        int code = s * 256 + nt * 16 + (lane & 15);
        int d0   = cc * 32 + (lane >> 4) * 8;
        const float* cr = cb + (size_t)code * EMB_DIM + d0;
        f16x8 v;
#pragma unroll
        for (int j = 0; j < 8; ++j) v[j] = (_Float16)(cr[j] * 1024.0f);
        _Float16* Bt = (_Float16*)ws + WS_BT_HOFF;
        *(f16x8*)(Bt + ((((size_t)(s * 8 + cc) * 16 + nt) * 64 + lane) * 8)) = v;
    }
}

// ---------------------------------------------------------------------------
// K1: MFMA candidate filter — 1024 blocks x 32 queries.
// ROUND-8 BUGFIX: A_lds fragment slot index is (c*2 + mt) — 8 chunks x 2
// m-tiles x 64 lanes = exactly 1024 f16x8 slots. Round 8 kept the 64-query
// stride (c*4 + mt), addressing up to slot 1919: ~14 KB OOB, trampling
// wm/cnt_s/bidx_s/bval_s -> garbage candidates -> kk=-1 -> absmax 1024.
// Mapping re-derived: read lane l'=kh*16+r of slot (c*2+mt) needs
// A[mt*16+r][c*32+kh*8+j]; write places query q=mt*16+r dims c*32+jg*8 at
// position jg*16+(q&15) -> jg=kh, q&15=r, q>>4=mt. Consistent.
// Block covers ALL 4 slabs, so block-min == global min (proof unchanged).
__global__ __launch_bounds__(256, 4) void k_filter(const float* __restrict__ z,
                                                   float* __restrict__ ws,
                                                   float* __restrict__ out) {
    __shared__ __attribute__((aligned(16))) _Float16 A_lds[1024 * 8];  // 16 KB
    __shared__ float wm[256];
    __shared__ float rmin_s[32];
    __shared__ float tq_s[32];
    __shared__ float thr_s[32];
    __shared__ int   cnt_s[32];
    __shared__ int   bidx_s[32][CAND_CAP];   // 4 KB
    __shared__ float bval_s[32][CAND_CAP];   // 4 KB

    const int tid = threadIdx.x;
    const int w = tid >> 6, l = tid & 63;
    const int qb = blockIdx.x, nq0 = qb * 32;
    const int bb = nq0 >> 10, p0 = nq0 & 1023;

    const f16x8* B8 = (const f16x8*)((const _Float16*)ws + WS_BT_HOFF);
    f16x8* Al = (f16x8*)A_lds;

    // prologue: issue B loads for steps 0,1 so they fly under A staging
    f16x8 b[3][4];
#pragma unroll
    for (int t = 0; t < 2; ++t)
#pragma unroll
        for (int nt = 0; nt < 4; ++nt)
            b[t][nt] = B8[((size_t)(t * 16) + w * 4 + nt) * 64 + l];

    // ---- stage A from fp32 z + s1 partial ----
    // lane -> (q = l&31, dh = l>>5); wave w covers d in [w*64, w*64+64).
    {
        const int q = l & 31, dh = l >> 5;
        const int mt = q >> 4;
        const float* zq = z + (size_t)bb * EMB_DIM * HW + p0 + q;
        float s1p = 0.0f;
#pragma unroll
        for (int jg = 0; jg < 4; ++jg) {
            const int d0 = w * 64 + dh * 32 + jg * 8;
            float v[8];
#pragma unroll
            for (int j = 0; j < 8; ++j) v[j] = zq[(size_t)(d0 + j) * HW];
            f16x8 g;
#pragma unroll
            for (int j = 0; j < 8; ++j) { g[j] = (_Float16)v[j]; s1p += fabsf(v[j]); }
            const int c = w * 2 + dh;            // chunk = d0>>5
            Al[(c * 2 + mt) * 64 + jg * 16 + (q & 15)] = g;
        }
        wm[tid] = s1p;
    }
    if (tid < 32) { cnt_s[tid] = 0; rmin_s[tid] = 3.4e38f; }
    __syncthreads();
    if (tid < 32) {
        float s1 = wm[tid];
#pragma unroll
        for (int i = 1; i < 8; ++i) s1 += wm[tid + 32 * i];
        tq_s[tid] = fmaf(T_SLOPE, s1, T_BIAS);
    }
    __syncthreads();

    const float* cn = ws + WS_CNORM_OFF;
    f32x4 acc[2][4];
#pragma unroll
    for (int mt = 0; mt < 2; ++mt)
#pragma unroll
        for (int nt = 0; nt < 4; ++nt) acc[mt][nt] = (f32x4)(0.0f);

#pragma unroll
    for (int t = 0; t < 32; ++t) {           // t = slab*8 + chunk
        const int c = t & 7, s = t >> 3;
        if (t + 2 < 32) {                    // depth-2 B prefetch
            const int t2 = t + 2;
#pragma unroll
            for (int nt = 0; nt < 4; ++nt)
                b[t2 % 3][nt] = B8[((size_t)(t2 * 16) + w * 4 + nt) * 64 + l];
        }
#pragma unroll
        for (int mt = 0; mt < 2; ++mt) {
            f16x8 av = Al[(c * 2 + mt) * 64 + l];
#pragma unroll
            for (int nt = 0; nt < 4; ++nt)
                acc[mt][nt] = __builtin_amdgcn_mfma_f32_16x16x32_f16(av, b[t % 3][nt], acc[mt][nt], 0, 0, 0);
        }
        if (c == 7) {
            // ---- slab epilogue (B loads for next slab already in flight) ----
            float c2[4];
#pragma unroll
            for (int nt = 0; nt < 4; ++nt)
                c2[nt] = cn[s * 256 + (w * 4 + nt) * 16 + (l & 15)];
            float vmin[2][4];
#pragma unroll
            for (int mt = 0; mt < 2; ++mt)
#pragma unroll
                for (int reg = 0; reg < 4; ++reg) vmin[mt][reg] = 3.4e38f;
#pragma unroll
            for (int mt = 0; mt < 2; ++mt)
#pragma unroll
                for (int nt = 0; nt < 4; ++nt)
#pragma unroll
                    for (int reg = 0; reg < 4; ++reg) {
                        float sv = fmaf(-0.001953125f, acc[mt][nt][reg], c2[nt]);  // -2/1024
                        acc[mt][nt][reg] = sv;
                        vmin[mt][reg] = fminf(vmin[mt][reg], sv);
                    }
#pragma unroll
            for (int msk = 1; msk < 16; msk <<= 1)
#pragma unroll
                for (int mt = 0; mt < 2; ++mt)
#pragma unroll
                    for (int reg = 0; reg < 4; ++reg)
                        vmin[mt][reg] = fminf(vmin[mt][reg], __shfl_xor(vmin[mt][reg], msk, 64));
            if ((l & 15) == 0) {
#pragma unroll
                for (int mt = 0; mt < 2; ++mt)
#pragma unroll
                    for (int reg = 0; reg < 4; ++reg)
                        wm[w * 32 + mt * 16 + (l >> 4) * 4 + reg] = vmin[mt][reg];
            }
            __syncthreads();
            if (tid < 32) {
                float smin = fminf(fminf(wm[tid], wm[32 + tid]),
                                   fminf(wm[64 + tid], wm[96 + tid]));
                float rm = fminf(rmin_s[tid], smin);
                rmin_s[tid] = rm;
                thr_s[tid] = rm + tq_s[tid];
            }
            __syncthreads();
            // append candidates under running threshold
#pragma unroll
            for (int mt = 0; mt < 2; ++mt)
#pragma unroll
                for (int reg = 0; reg < 4; ++reg) {
                    int m = mt * 16 + (l >> 4) * 4 + reg;
                    float th = thr_s[m];
#pragma unroll
                    for (int nt = 0; nt < 4; ++nt) {
                        float sv = acc[mt][nt][reg];
                        if (sv <= th) {
                            int kg = s * 256 + (w * 4 + nt) * 16 + (l & 15);
                            int pos = atomicAdd(&cnt_s[m], 1);
                            if (pos < CAND_CAP) { bidx_s[m][pos] = kg; bval_s[m][pos] = sv; }
                        }
                    }
                }
            // re-zero accumulators for next slab
#pragma unroll
            for (int mt = 0; mt < 2; ++mt)
#pragma unroll
                for (int nt = 0; nt < 4; ++nt) acc[mt][nt] = (f32x4)(0.0f);
        }
    }
    __syncthreads();   // all appends visible
    if (tid < 32) {
        int n = nq0 + tid;
        int c = cnt_s[tid];
        int* cnt_g  = (int*)ws + WS_CNT_IOFF;
        int* cand_g = (int*)ws + WS_CAND_IOFF;
        if (c > CAND_CAP) {
            cnt_g[n] = 1025;                  // overflow sentinel -> full rescan
        } else {
            float th = thr_s[tid];            // global min + T (after slab 3)
            int m = 0, keep = 0;
            for (int j = 0; j < c; ++j) {
                if (bval_s[tid][j] <= th) {
                    cand_g[(size_t)n * CAND_CAP + m] = bidx_s[tid][j];
                    if (m == 0) keep = bidx_s[tid][j];
                    ++m;
                }
            }
            if (m == 1) {
                out[IDX_OFF + n] = (float)keep;   // resolved here
                cnt_g[n] = 0;
            } else {
                cnt_g[n] = m;
            }
        }
    }
}

// ---------------------------------------------------------------------------
// K2: fused exact znorm + rescore + gather + loss. (unchanged, passing r5/r7)
__global__ __launch_bounds__(256) void k_resgather(const float* __restrict__ z,
                                                   const float* __restrict__ cb,
                                                   float* __restrict__ ws,
                                                   float* __restrict__ out) {
    __shared__ __attribute__((aligned(16))) float z_lds[256][64];   // 64 KB
    __shared__ float s_half[64][33];                                // 8.4 KB
    __shared__ int   idx_s[64];
    __shared__ int   c_s[64];
    __shared__ int   offI[64];
    __shared__ int   ovf_s[64];
    __shared__ float zh_s[64];
    __shared__ float zn_s[64];
    __shared__ unsigned long long key_s[64];
    __shared__ float s_red[4];
    __shared__ int   work_s;

    const int tid = threadIdx.x;
    const int w = tid >> 6, l = tid & 63;
    const int n0 = blockIdx.x * 64;
    const int b = n0 >> 10, p0 = n0 & 1023;
    const int* cnt  = (const int*)ws + WS_CNT_IOFF;
    const int* cand = (const int*)ws + WS_CAND_IOFF;
    const float* cn = ws + WS_CNORM_OFF;

    if (tid < 64) {   // wave 0: per-query state + prefix scan + work flag
        int c = cnt[n0 + tid];
        int ov = (c > CAND_CAP) ? 1 : 0;
        ovf_s[tid] = ov;
        int cc = (ov || c < 2) ? 0 : c;
        c_s[tid] = cc;
        key_s[tid] = ~0ULL;
        if (cc == 0 && !ov) idx_s[tid] = (int)out[IDX_OFF + n0 + tid];  // filter-resolved
        int v = cc;
#pragma unroll
        for (int off = 1; off < 64; off <<= 1) {
            int u = __shfl_up(v, off, 64);
            if (l >= off) v += u;
        }
        offI[tid] = v;
        unsigned long long ball = __ballot(ov != 0);
        if (tid == 63) work_s = v + (ball ? 1 : 0);
    }

    // stage z tile: [d][q] fp32, float4 coalesced (exact bits); always needed
    {
        const float* zb = z + (size_t)b * EMB_DIM * HW + p0;
        const int q4 = tid & 15, g = tid >> 4;
#pragma unroll 4
        for (int r = 0; r < 16; ++r) {
            int d = r * 16 + g;
            float4 vv = *(const float4*)(zb + (size_t)d * HW + q4 * 4);
            *(float4*)&z_lds[d][q4 * 4] = vv;
        }
    }
    __syncthreads();

    if (work_s != 0) {
        // znorm from z_lds: exact pairwise tree, 2 threads/query (128-d seam)
        float hf0 = 0.0f;
        if (tid < 128) {
            const int q = tid & 63, h = tid >> 6;
            float r[8];
#pragma unroll
            for (int j = 0; j < 8; ++j) {
                float v = z_lds[h * 128 + j][q];
                r[j] = __fmul_rn(v, v);
            }
            for (int i = 8; i < 128; i += 8)
#pragma unroll
                for (int j = 0; j < 8; ++j) {
                    float v = z_lds[h * 128 + i + j][q];
                    r[j] = __fadd_rn(r[j], __fmul_rn(v, v));
                }
            float hf = __fadd_rn(__fadd_rn(__fadd_rn(r[0], r[1]), __fadd_rn(r[2], r[3])),
                                 __fadd_rn(__fadd_rn(r[4], r[5]), __fadd_rn(r[6], r[7])));
            if (h) zh_s[q] = hf; else hf0 = hf;
        }
        __syncthreads();
        if (tid < 64) zn_s[tid] = __fadd_rn(hf0, zh_s[tid]);   // exact fadd(half0, half1)
        __syncthreads();

        // candidate-per-thread exact rescore
        const int C = offI[63];
        for (int t = tid; t < C; t += 256) {
            int lo = 0, hi = 63;
            while (lo < hi) { int mid = (lo + hi) >> 1; if (offI[mid] > t) hi = mid; else lo = mid + 1; }
            const int m = lo;
            const int j = t - (m ? offI[m - 1] : 0);
            const int n = n0 + m;
            const int kk = cand[(size_t)n * CAND_CAP + j];
            const float* r = cb + (size_t)kk * EMB_DIM;
            float dot = 0.0f;
#pragma unroll 8
            for (int d = 0; d < EMB_DIM; ++d)
                dot = fmaf(z_lds[d][m], r[d], dot);
            float t1 = __fadd_rn(zn_s[m], cn[kk]);
            float sv = __fadd_rn(t1, __fmul_rn(-2.0f, dot));
            unsigned ue = __float_as_uint(sv);
            ue = (ue >> 31) ? ~ue : (ue | 0x80000000u);
            atomicMin(&key_s[m], ((unsigned long long)ue << 32) | (unsigned)kk);
        }

        // overflow queries (rare): distributed exact full scan, wave per query
        for (int m = w; m < 64; m += 4) {
            if (!ovf_s[m]) continue;
            const float z2 = zn_s[m];
            float sv = 3.4e38f; int kk = NUM_EMB;
            for (int k0 = l; k0 < NUM_EMB; k0 += 64) {
                const float* r = cb + (size_t)k0 * EMB_DIM;
                float dot = 0.0f;
#pragma unroll 8
                for (int d = 0; d < EMB_DIM; ++d)
                    dot = fmaf(z_lds[d][m], r[d], dot);
                float t1 = __fadd_rn(z2, cn[k0]);
                float s2 = __fadd_rn(t1, __fmul_rn(-2.0f, dot));
                if (s2 < sv) { sv = s2; kk = k0; }   // ascending k: < keeps first
            }
#pragma unroll
            for (int off = 32; off; off >>= 1) {
                float osv = __shfl_xor(sv, off, 64);
                int   okk = __shfl_xor(kk, off, 64);
                if (osv < sv || (osv == sv && okk < kk)) { sv = osv; kk = okk; }
            }
            if (l == 0) {
                unsigned ue = __float_as_uint(sv);
                ue = (ue >> 31) ? ~ue : (ue | 0x80000000u);
                key_s[m] = ((unsigned long long)ue << 32) | (unsigned)kk;
            }
        }
        __syncthreads();
        if (tid < 64 && (c_s[tid] > 0 || ovf_s[tid])) {
            int kk = (int)(unsigned)(key_s[tid] & 0xFFFFFFFFULL);
            idx_s[tid] = kk;
            out[IDX_OFF + n0 + tid] = (float)kk;
        }
        __syncthreads();
    }

    // ---- gather phase: per-thread arithmetic/order bit-identical ----
    const int p    = tid & 63;
    const int cgrp = tid >> 6;
    const int row  = tid >> 2;
    const int q4g  = tid & 3;
    float* orow = out + (size_t)b * EMB_DIM * HW + p0 + p;

    float acc = 0.0f;
#pragma unroll 1
    for (int d0 = 0; d0 < EMB_DIM; d0 += 64) {
        const float* cr = cb + (size_t)idx_s[row] * EMB_DIM + d0;
#pragma unroll 1
        for (int h = 0; h < 2; ++h) {
#pragma unroll
            for (int pass = 0; pass < 2; ++pass) {
                int s = q4g + pass * 4;
                int gg = s >> 1, j00 = (s & 1) * 4;
                *(float4*)&s_half[row][gg * 8 + j00] = *(const float4*)(cr + gg * 16 + h * 8 + j00);
            }
            __syncthreads();
#pragma unroll
            for (int j0 = 0; j0 < 8; ++j0) {
                int c = cgrp * 16 + h * 8 + j0;
                float zq = s_half[p][cgrp * 8 + j0];
                float zv = z_lds[d0 + c][p];
                float d  = zq - zv;
                orow[(size_t)(d0 + c) * HW] = zv + d;
                acc += d * d;
            }
            __syncthreads();
        }
    }
#pragma unroll
    for (int off = 32; off > 0; off >>= 1) acc += __shfl_down(acc, off, 64);
    if ((tid & 63) == 0) s_red[tid >> 6] = acc;
    __syncthreads();
    if (tid == 0) {
        atomicAdd(ws, s_red[0] + s_red[1] + s_red[2] + s_red[3]);
        __threadfence();
        unsigned old = atomicAdd((unsigned int*)ws + 1, 1u);
        if (old == 511u) {
            float total = atomicAdd(ws, 0.0f);
            out[LOSS_OFF] = 1.25f * (total * (1.0f / 8388608.0f));
        }
    }
}

// ---------------------------------------------------------------------------
extern "C" void kernel_launch(void* const* d_in, const int* in_sizes, int n_in,
                              void* d_out, int out_size, void* d_ws, size_t ws_size,
                              hipStream_t stream) {
    const float* z  = (const float*)d_in[0];
    const float* cb = (const float*)d_in[1];
    float* out = (float*)d_out;
    float* ws  = (float*)d_ws;

    k_prep     <<<132,  256, 0, stream>>>(cb, ws);
    k_filter   <<<1024, 256, 0, stream>>>(z, ws, out);
    k_resgather<<<512,  256, 0, stream>>>(z, cb, ws, out);
}